// Round 2
// baseline (507.221 us; speedup 1.0000x reference)
//
#include <hip/hip_runtime.h>
#include <hip/hip_bf16.h>

typedef unsigned short ushort;
typedef unsigned int uint;
typedef __bf16 bf16x8 __attribute__((ext_vector_type(8)));
typedef float f32x4 __attribute__((ext_vector_type(4)));
typedef ushort ushort8 __attribute__((ext_vector_type(8)));

#define LOG2E 1.4426950408889634f
#define MFMA16(a,b,c) __builtin_amdgcn_mfma_f32_16x16x32_bf16((a),(b),(c),0,0,0)

static __device__ __forceinline__ uint packbf(float lo, float hi) {
  union { __bf16 h[2]; uint u; } x;
  x.h[0] = (__bf16)lo; x.h[1] = (__bf16)hi;
  return x.u;
}

// ---------------------------------------------------------------------------
// cast 4 weight matrices [256x256] f32 -> bf16 (contiguous in wsW)
// ---------------------------------------------------------------------------
__global__ __launch_bounds__(256) void cast_weights(
    const float* __restrict__ W0, const float* __restrict__ W1,
    const float* __restrict__ W2, const float* __restrict__ W3,
    __bf16* __restrict__ out)
{
  const int which = blockIdx.y;
  const float* src = which == 0 ? W0 : which == 1 ? W1 : which == 2 ? W2 : W3;
  const int i = (blockIdx.x * 256 + threadIdx.x) * 4;
  f32x4 v = *(const f32x4*)(src + i);
  union { __bf16 h[4]; uint u[2]; } x;
  #pragma unroll
  for (int j = 0; j < 4; j++) x.h[j] = (__bf16)v[j];
  *(uint*)(out + (size_t)which * 65536 + i) = x.u[0];
  *(uint*)(out + (size_t)which * 65536 + i + 2) = x.u[1];
}

// ---------------------------------------------------------------------------
// GEMM: out[n][d] = sum_c A[n][c] * W[d][c] + bias[d]
// A: f32 (cast in-reg) or bf16; W: bf16 (preconverted); bias f32;
// out: bf16 (ws) or f32 (d_out)
// block: 256 thr = 4 waves; block tile 64n x 128d; wave tile 32n x 64d
// ---------------------------------------------------------------------------
template<bool A_F32, bool OUT_F32>
__global__ __launch_bounds__(256) void gemm256(
    const void* __restrict__ A_, const ushort* __restrict__ W,
    const float* __restrict__ bias, void* __restrict__ out_)
{
  const int wid = threadIdx.x >> 6;
  const int lane = threadIdx.x & 63;
  const int q = lane & 15, g = lane >> 4;
  const int nb = blockIdx.x * 64 + (wid >> 1) * 32;
  const int db = blockIdx.y * 128 + (wid & 1) * 64;

  f32x4 acc[2][4];
  #pragma unroll
  for (int a = 0; a < 2; a++)
    #pragma unroll
    for (int b = 0; b < 4; b++) acc[a][b] = f32x4{0.f,0.f,0.f,0.f};

  const ushort* W0 = W + (size_t)(db + q) * 256 + g * 8;

  #pragma unroll
  for (int c0 = 0; c0 < 256; c0 += 32) {
    bf16x8 a0, a1;
    if constexpr (A_F32) {
      const float* Ar0 = (const float*)A_ + (size_t)(nb + q) * 256 + g * 8 + c0;
      const float* Ar1 = (const float*)A_ + (size_t)(nb + 16 + q) * 256 + g * 8 + c0;
      f32x4 u0 = *(const f32x4*)Ar0, u1 = *(const f32x4*)(Ar0 + 4);
      f32x4 w0 = *(const f32x4*)Ar1, w1 = *(const f32x4*)(Ar1 + 4);
      #pragma unroll
      for (int j = 0; j < 4; j++) {
        a0[j] = (__bf16)u0[j]; a0[4 + j] = (__bf16)u1[j];
        a1[j] = (__bf16)w0[j]; a1[4 + j] = (__bf16)w1[j];
      }
    } else {
      const ushort* Ar0 = (const ushort*)A_ + (size_t)(nb + q) * 256 + g * 8 + c0;
      const ushort* Ar1 = (const ushort*)A_ + (size_t)(nb + 16 + q) * 256 + g * 8 + c0;
      a0 = *(const bf16x8*)Ar0;
      a1 = *(const bf16x8*)Ar1;
    }
    #pragma unroll
    for (int df = 0; df < 4; df++) {
      bf16x8 w = *(const bf16x8*)(W0 + df * 16 * 256 + c0);
      acc[0][df] = MFMA16(a0, w, acc[0][df]);
      acc[1][df] = MFMA16(a1, w, acc[1][df]);
    }
  }
  #pragma unroll
  for (int df = 0; df < 4; df++) {
    float bv = bias[db + df * 16 + q];
    #pragma unroll
    for (int nf = 0; nf < 2; nf++)
      #pragma unroll
      for (int r = 0; r < 4; r++) {
        int row = nb + nf * 16 + g * 4 + r;
        float val = acc[nf][df][r] + bv;
        if constexpr (OUT_F32)
          ((float*)out_)[(size_t)row * 256 + db + df * 16 + q] = val;
        else
          ((__bf16*)out_)[(size_t)row * 256 + db + df * 16 + q] = (__bf16)val;
      }
  }
}

// ---------------------------------------------------------------------------
// Flash attention with distance-window mask.
// grid: 256 blocks (batch = bid&3 for XCD L2 locality), 4 waves, 16 q rows/wave.
// Swapped QK^T: S^T = mfma(K, Q): lane holds col q = lane&15, rows = keys.
// ---------------------------------------------------------------------------
__global__ __launch_bounds__(256, 1) void attn_kernel(
    const ushort* __restrict__ Q, const ushort* __restrict__ K,
    const ushort* __restrict__ V,
    const float* __restrict__ kp,   // kpts_t1_pred  f32 [B*4096][2]
    const float* __restrict__ ka,   // kpts_t1_actual
    const int* __restrict__ iter_idx,
    __bf16* __restrict__ matched,   // ws bf16 [B*4096][256]
    float* __restrict__ out_flow, float* __restrict__ out_conf)
{
  __shared__ __align__(16) ushort VT[2][256][40];   // V^T tiles (double buf), pad 40

  const int tid = threadIdx.x;
  const int wid = tid >> 6, lane = tid & 63;
  const int q = lane & 15, g = lane >> 4;
  const int batch = blockIdx.x & 3;        // XCD-friendly: XCD k streams batch k&3
  const int qtile = blockIdx.x >> 2;
  const int qrow = batch * 4096 + qtile * 64 + wid * 16;

  const int idx = *iter_idx;
  const float win = (idx == 0) ? 64.0f : fmaxf(4.0f, ldexpf(32.0f, 1 - idx));

  // Q fragments (B operand of swapped QK): col q = lane&15
  bf16x8 qf[8];
  const ushort* qptr = Q + (size_t)(qrow + q) * 256 + g * 8;
  #pragma unroll
  for (int mf = 0; mf < 8; mf++) qf[mf] = *(const bf16x8*)(qptr + mf * 32);

  const float2* kp2 = (const float2*)kp;
  const float pu = kp2[qrow + q].x;
  const float pv = kp2[qrow + q].y;

  f32x4 O[16];
  #pragma unroll
  for (int i = 0; i < 16; i++) O[i] = f32x4{0.f,0.f,0.f,0.f};
  float m_run = -1e9f, l_run = 0.f, u_run = 0.f, v_run = 0.f;

  const ushort* Kbase = K + (size_t)batch * 4096 * 256;
  const ushort* Vbase = V + (size_t)batch * 4096 * 256;
  const float2* ka2 = (const float2*)ka + (size_t)batch * 4096;

  // V^T staging map: thread -> key pair (2*skp, 2*skp+1), d chunks
  const int skp = tid & 15;
  const int sdb = tid >> 4;   // 0..15

  // stage tile 0
  {
    #pragma unroll
    for (int it = 0; it < 2; it++) {
      int d0 = sdb * 8 + it * 128;
      ushort8 v0 = *(const ushort8*)(Vbase + (size_t)(2 * skp) * 256 + d0);
      ushort8 v1 = *(const ushort8*)(Vbase + (size_t)(2 * skp + 1) * 256 + d0);
      #pragma unroll
      for (int j = 0; j < 8; j++)
        *(uint*)&VT[0][d0 + j][2 * skp] = ((uint)v1[j] << 16) | (uint)v0[j];
    }
  }
  __syncthreads();

  int cur = 0;
  for (int t = 0; t < 128; t++) {
    const int kb = t * 32;

    // prefetch next V tile into regs
    ushort8 pf0a, pf0b, pf1a, pf1b;
    if (t < 127) {
      const ushort* vb = Vbase + (size_t)(kb + 32 + 2 * skp) * 256;
      pf0a = *(const ushort8*)(vb + sdb * 8);
      pf1a = *(const ushort8*)(vb + 256 + sdb * 8);
      pf0b = *(const ushort8*)(vb + sdb * 8 + 128);
      pf1b = *(const ushort8*)(vb + 256 + sdb * 8 + 128);
    }

    // S^T = K . Q^T  (two 16-key fragments, split accumulators for ILP)
    const ushort* k0p = Kbase + (size_t)(kb + q) * 256 + g * 8;
    const ushort* k1p = Kbase + (size_t)(kb + 16 + q) * 256 + g * 8;
    f32x4 s0a = {0.f,0.f,0.f,0.f}, s0b = {0.f,0.f,0.f,0.f};
    f32x4 s1a = {0.f,0.f,0.f,0.f}, s1b = {0.f,0.f,0.f,0.f};
    #pragma unroll
    for (int mf = 0; mf < 8; mf += 2) {
      bf16x8 ka0 = *(const bf16x8*)(k0p + mf * 32);
      bf16x8 kb0 = *(const bf16x8*)(k0p + (mf + 1) * 32);
      bf16x8 ka1 = *(const bf16x8*)(k1p + mf * 32);
      bf16x8 kb1 = *(const bf16x8*)(k1p + (mf + 1) * 32);
      s0a = MFMA16(ka0, qf[mf], s0a);
      s0b = MFMA16(kb0, qf[mf + 1], s0b);
      s1a = MFMA16(ka1, qf[mf], s1a);
      s1b = MFMA16(kb1, qf[mf + 1], s1b);
    }

    // mask + scale; keys for this lane: frag0 k=4g+r, frag1 k=16+4g+r
    float aus[8], avs[8], sv[8];
    #pragma unroll
    for (int r = 0; r < 4; r++) {
      float2 c0 = ka2[kb + 4 * g + r];
      aus[r] = c0.x; avs[r] = c0.y;
      float du = fabsf(pu - aus[r]), dv = fabsf(pv - avs[r]);
      float sr = s0a[r] + s0b[r];
      sv[r] = (fmaxf(du, dv) < win) ? sr * 0.0625f : -1e9f;

      float2 c1 = ka2[kb + 16 + 4 * g + r];
      aus[4 + r] = c1.x; avs[4 + r] = c1.y;
      du = fabsf(pu - aus[4 + r]); dv = fabsf(pv - avs[4 + r]);
      sr = s1a[r] + s1b[r];
      sv[4 + r] = (fmaxf(du, dv) < win) ? sr * 0.0625f : -1e9f;
    }

    // online softmax (per column q = lane&15, spread over 4 lane groups)
    float mt = fmaxf(fmaxf(fmaxf(sv[0], sv[1]), fmaxf(sv[2], sv[3])),
                     fmaxf(fmaxf(sv[4], sv[5]), fmaxf(sv[6], sv[7])));
    mt = fmaxf(mt, __shfl_xor(mt, 16));
    mt = fmaxf(mt, __shfl_xor(mt, 32));
    if (__any(mt > m_run)) {
      float m_new = fmaxf(m_run, mt);
      float scale = exp2f((m_run - m_new) * LOG2E);
      l_run *= scale; u_run *= scale; v_run *= scale;
      float s_r[4];
      #pragma unroll
      for (int r = 0; r < 4; r++) s_r[r] = __shfl(scale, 4 * g + r);
      #pragma unroll
      for (int df = 0; df < 16; df++)
        #pragma unroll
        for (int r = 0; r < 4; r++) O[df][r] *= s_r[r];
      m_run = m_new;
    }

    float p[8];
    #pragma unroll
    for (int i = 0; i < 8; i++) p[i] = exp2f((sv[i] - m_run) * LOG2E);
    #pragma unroll
    for (int i = 0; i < 8; i++) {
      l_run += p[i];
      u_run += p[i] * aus[i];
      v_run += p[i] * avs[i];
    }

    // pack P^T(C layout) -> A-operand layout via lane exchange
    uint d0 = packbf(p[0], p[1]), d1 = packbf(p[2], p[3]);
    uint d2 = packbf(p[4], p[5]), d3 = packbf(p[6], p[7]);
    int srcA = q + ((g & 1) << 5);
    int srcB = srcA + 16;
    uint x0 = (uint)__shfl((int)d0, srcA), x1 = (uint)__shfl((int)d1, srcA);
    uint x2 = (uint)__shfl((int)d0, srcB), x3 = (uint)__shfl((int)d1, srcB);
    uint y0 = (uint)__shfl((int)d2, srcA), y1 = (uint)__shfl((int)d3, srcA);
    uint y2 = (uint)__shfl((int)d2, srcB), y3 = (uint)__shfl((int)d3, srcB);
    union { uint i[4]; bf16x8 v; } af;
    bool lo = (g < 2);
    af.i[0] = lo ? x0 : y0; af.i[1] = lo ? x1 : y1;
    af.i[2] = lo ? x2 : y2; af.i[3] = lo ? x3 : y3;

    // PV: O[16q x 16d] += P[16q x 32k] * V^T-frag
    #pragma unroll
    for (int df = 0; df < 16; df++) {
      bf16x8 vf = *(const bf16x8*)&VT[cur][df * 16 + q][g * 8];
      O[df] = MFMA16(af.v, vf, O[df]);
    }

    // write staged next tile, flip buffers
    if (t < 127) {
      #pragma unroll
      for (int j = 0; j < 8; j++) {
        *(uint*)&VT[cur ^ 1][sdb * 8 + j][2 * skp] = ((uint)pf1a[j] << 16) | (uint)pf0a[j];
        *(uint*)&VT[cur ^ 1][sdb * 8 + 128 + j][2 * skp] = ((uint)pf1b[j] << 16) | (uint)pf0b[j];
      }
      __syncthreads();
      cur ^= 1;
    }
  }

  // final reductions across the 4 lane groups
  l_run += __shfl_xor(l_run, 16); l_run += __shfl_xor(l_run, 32);
  u_run += __shfl_xor(u_run, 16); u_run += __shfl_xor(u_run, 32);
  v_run += __shfl_xor(v_run, 16); v_run += __shfl_xor(v_run, 32);
  float rinv = 1.0f / l_run;
  float conf = (m_run > -5e8f) ? 1.0f : 0.0f;

  if (g == 0) {   // lanes 0..15 own column q
    int row = qrow + q;
    float mu = u_run * rinv, mv = v_run * rinv;
    float fu = (mu - pu) * conf, fv = (mv - pv) * conf;
    ((float2*)out_flow)[row] = float2{fu, fv};
    out_conf[row] = conf;
  }

  float rinv_r[4];
  #pragma unroll
  for (int r = 0; r < 4; r++) rinv_r[r] = __shfl(rinv, 4 * g + r);
  #pragma unroll
  for (int df = 0; df < 16; df++)
    #pragma unroll
    for (int r = 0; r < 4; r++) {
      int row = qrow + 4 * g + r;
      matched[(size_t)row * 256 + df * 16 + q] = (__bf16)(O[df][r] * rinv_r[r]);
    }
}

// ---------------------------------------------------------------------------
// geo MLP: h = silu(geo_in @ Wg1^T + bg1); geo = h @ Wg2^T + bg2
// ---------------------------------------------------------------------------
__global__ __launch_bounds__(256) void geo_kernel(
    const float* __restrict__ flow, const float* __restrict__ conf_in,
    const float* __restrict__ Wg1, const float* __restrict__ bg1,
    const float* __restrict__ Wg2, const float* __restrict__ bg2,
    float* __restrict__ out_geo)
{
  __shared__ float w1[32][3], b1[32], b2[32];
  __shared__ __align__(16) float w2[32][32];
  int tid = threadIdx.x;
  for (int i = tid; i < 96; i += 256) w1[i / 3][i % 3] = Wg1[i];
  if (tid < 32) { b1[tid] = bg1[tid]; b2[tid] = bg2[tid]; }
  for (int i = tid; i < 1024; i += 256) w2[i / 32][i % 32] = Wg2[i];
  __syncthreads();

  int row = blockIdx.x * 256 + tid;
  float2 f = ((const float2*)flow)[row];
  float c = conf_in[row];
  float h[32];
  #pragma unroll
  for (int j = 0; j < 32; j++) {
    float x = w1[j][0] * f.x + w1[j][1] * f.y + w1[j][2] * c + b1[j];
    h[j] = x / (1.f + __expf(-x));
  }
  #pragma unroll
  for (int o = 0; o < 32; o += 2) {
    float s0 = b2[o], s1 = b2[o + 1];
    #pragma unroll
    for (int j = 0; j < 32; j += 4) {
      f32x4 wa = *(const f32x4*)&w2[o][j];
      f32x4 wb = *(const f32x4*)&w2[o + 1][j];
      s0 += wa[0]*h[j] + wa[1]*h[j+1] + wa[2]*h[j+2] + wa[3]*h[j+3];
      s1 += wb[0]*h[j] + wb[1]*h[j+1] + wb[2]*h[j+2] + wb[3]*h[j+3];
    }
    ((float2*)out_geo)[((size_t)row * 32 + o) >> 1] = float2{s0, s1};
  }
}

// ---------------------------------------------------------------------------
extern "C" void kernel_launch(void* const* d_in, const int* in_sizes, int n_in,
                              void* d_out, int out_size, void* d_ws, size_t ws_size,
                              hipStream_t stream) {
  const float* nodes_t  = (const float*)d_in[0];
  const float* nodes_t1 = (const float*)d_in[1];
  const float* kpred    = (const float*)d_in[2];
  const float* kact     = (const float*)d_in[3];
  const float* Wq = (const float*)d_in[4];  const float* bq = (const float*)d_in[5];
  const float* Wk = (const float*)d_in[6];  const float* bk = (const float*)d_in[7];
  const float* Wv = (const float*)d_in[8];  const float* bv = (const float*)d_in[9];
  const float* Wm = (const float*)d_in[10]; const float* bm = (const float*)d_in[11];
  const float* Wg1= (const float*)d_in[12]; const float* bg1= (const float*)d_in[13];
  const float* Wg2= (const float*)d_in[14]; const float* bg2= (const float*)d_in[15];
  const int* iter = (const int*)d_in[16];

  float* out_merged = (float*)d_out;                 // 4*4096*256
  float* out_geo  = out_merged + 4 * 4096 * 256;     // 4*4096*32
  float* out_flow = out_geo + 4 * 4096 * 32;         // 4*4096*2
  float* out_conf = out_flow + 4 * 4096 * 2;         // 4*4096

  ushort* wsQ = (ushort*)d_ws;        // bf16 4194304 el each
  ushort* wsK = wsQ + 4194304;
  ushort* wsV = wsK + 4194304;
  ushort* wsM = wsV + 4194304;
  ushort* wsW = wsM + 4194304;        // bf16 4*65536 (Wq,Wk,Wv,Wm)

  dim3 cg(64, 4, 1);
  cast_weights<<<cg, 256, 0, stream>>>(Wq, Wk, Wv, Wm, (__bf16*)wsW);

  dim3 gg(256, 2, 1);
  gemm256<true,  false><<<gg, 256, 0, stream>>>(nodes_t,  wsW,          bq, wsQ);
  gemm256<true,  false><<<gg, 256, 0, stream>>>(nodes_t1, wsW + 65536,  bk, wsK);
  gemm256<true,  false><<<gg, 256, 0, stream>>>(nodes_t1, wsW + 131072, bv, wsV);
  attn_kernel<<<256, 256, 0, stream>>>(wsQ, wsK, wsV, kpred, kact, iter,
                                       (__bf16*)wsM, out_flow, out_conf);
  gemm256<false, true ><<<gg, 256, 0, stream>>>(wsM, wsW + 196608, bm, out_merged);
  geo_kernel<<<64, 256, 0, stream>>>(out_flow, out_conf, Wg1, bg1, Wg2, bg2, out_geo);
}